// Round 5
// baseline (980.240 us; speedup 1.0000x reference)
//
#include <hip/hip_runtime.h>
#include <hip/hip_bf16.h>

typedef __attribute__((ext_vector_type(8))) short s16x8;
typedef __attribute__((ext_vector_type(4))) float f32x4;

#define GAS __attribute__((address_space(1)))
#define LAS __attribute__((address_space(3)))

#define WAITV(N) asm volatile("s_waitcnt vmcnt(" #N ")" ::: "memory")
#define BAR() __builtin_amdgcn_s_barrier()

__device__ __forceinline__ float b2f(unsigned short u) {
  union { unsigned int i; float f; } x; x.i = ((unsigned int)u) << 16; return x.f;
}
__device__ __forceinline__ unsigned short f2b(float f) {
  union { float f; unsigned int i; } x; x.f = f;
  unsigned int r = x.i + 0x7fffu + ((x.i >> 16) & 1u);
  return (unsigned short)(r >> 16);
}

// async global->LDS, 16B per lane; lds dest is wave-uniform base + lane*16
__device__ __forceinline__ void gl16(const unsigned short* g, unsigned short* l) {
  __builtin_amdgcn_global_load_lds((const GAS unsigned int*)g,
                                   (LAS unsigned int*)l, 16, 0, 0);
}

// ---------------- weight packing ----------------
__global__ __launch_bounds__(256) void pack_qkv_k(const float* __restrict__ wq,
                                                  const float* __restrict__ wk,
                                                  const float* __restrict__ wv,
                                                  unsigned short* __restrict__ dst) {
  int idx = blockIdx.x * 256 + threadIdx.x;   // n*512 + c
  int n = idx >> 9, c = idx & 511;
  int sel = n >> 9;
  int hn = n & 511;
  const float* src = sel == 0 ? wq : (sel == 1 ? wk : wv);
  float v = src[((hn >> 6) << 15) + (c << 6) + (hn & 63)];  // wq[h][c][d]
  dst[idx] = f2b(v);
}

// dst[n][k] = src[k][n], src is (K,N) row-major
__global__ __launch_bounds__(256) void pack_T_k(const float* __restrict__ src,
                                                unsigned short* __restrict__ dst,
                                                int K, int N) {
  int idx = blockIdx.x * 256 + threadIdx.x;
  int n = idx / K, k = idx % K;
  dst[idx] = f2b(src[(long long)k * N + n]);
}

// ---------------- layernorm (wave per row, C=512), fp32 input ----------------
__global__ __launch_bounds__(256) void ln_k(const float* __restrict__ in,
                                            const float* __restrict__ g,
                                            const float* __restrict__ bb,
                                            unsigned short* __restrict__ out) {
  int row = blockIdx.x * 4 + (threadIdx.x >> 6);
  int lane = threadIdx.x & 63;
  const float* p = in + (size_t)row * 512 + lane * 8;
  f32x4 a = *(const f32x4*)p;
  f32x4 b = *(const f32x4*)(p + 4);
  float vals[8] = {a.x, a.y, a.z, a.w, b.x, b.y, b.z, b.w};
  float s = 0.f, q = 0.f;
#pragma unroll
  for (int i = 0; i < 8; i++) { s += vals[i]; q += vals[i] * vals[i]; }
#pragma unroll
  for (int off = 1; off < 64; off <<= 1) {
    s += __shfl_xor(s, off);
    q += __shfl_xor(q, off);
  }
  float mean = s * (1.0f / 512.0f);
  float rstd = rsqrtf(q * (1.0f / 512.0f) - mean * mean + 1e-5f);
  const float* gp = g + lane * 8;
  const float* bp = bb + lane * 8;
  s16x8 o;
#pragma unroll
  for (int i = 0; i < 8; i++) o[i] = (short)f2b((vals[i] - mean) * rstd * gp[i] + bp[i]);
  *(s16x8*)(out + (size_t)row * 512 + lane * 8) = o;
}

// ---------------- layernorm, bf16 input ----------------
__global__ __launch_bounds__(256) void ln_b_k(const unsigned short* __restrict__ in,
                                              const float* __restrict__ g,
                                              const float* __restrict__ bb,
                                              unsigned short* __restrict__ out) {
  int row = blockIdx.x * 4 + (threadIdx.x >> 6);
  int lane = threadIdx.x & 63;
  s16x8 v8 = *(const s16x8*)(in + (size_t)row * 512 + lane * 8);
  float vals[8];
#pragma unroll
  for (int i = 0; i < 8; i++) vals[i] = b2f((unsigned short)v8[i]);
  float s = 0.f, q = 0.f;
#pragma unroll
  for (int i = 0; i < 8; i++) { s += vals[i]; q += vals[i] * vals[i]; }
#pragma unroll
  for (int off = 1; off < 64; off <<= 1) {
    s += __shfl_xor(s, off);
    q += __shfl_xor(q, off);
  }
  float mean = s * (1.0f / 512.0f);
  float rstd = rsqrtf(q * (1.0f / 512.0f) - mean * mean + 1e-5f);
  const float* gp = g + lane * 8;
  const float* bp = bb + lane * 8;
  s16x8 o;
#pragma unroll
  for (int i = 0; i < 8; i++) o[i] = (short)f2b((vals[i] - mean) * rstd * gp[i] + bp[i]);
  *(s16x8*)(out + (size_t)row * 512 + lane * 8) = o;
}

// ---------------- attention (one wave per (b,h); T=16, D=64) ----------------
__global__ __launch_bounds__(256) void attn_k(const unsigned short* __restrict__ qkv,
                                              unsigned short* __restrict__ o) {
  int w = (blockIdx.x << 2) + (threadIdx.x >> 6);
  int lane = threadIdx.x & 63;
  int b = w >> 3, h = w & 7;
  int t = lane >> 2, p = lane & 3;   // 4 lanes per query row, 16 d's each

  size_t rowq = (size_t)(b * 16 + t) * 1536 + h * 64 + p * 16;
  float q[16];
  {
    s16x8 q0 = *(const s16x8*)(qkv + rowq);
    s16x8 q1 = *(const s16x8*)(qkv + rowq + 8);
#pragma unroll
    for (int i = 0; i < 8; i++) {
      q[i] = b2f((unsigned short)q0[i]) * 0.125f;
      q[8 + i] = b2f((unsigned short)q1[i]) * 0.125f;
    }
  }
  float lg[16];
  size_t kbase = (size_t)(b * 16) * 1536 + 512 + h * 64 + p * 16;
#pragma unroll
  for (int s = 0; s < 16; s++) {
    const unsigned short* kp = qkv + kbase + (size_t)s * 1536;
    s16x8 k0 = *(const s16x8*)kp;
    s16x8 k1 = *(const s16x8*)(kp + 8);
    float d = 0.f;
#pragma unroll
    for (int i = 0; i < 8; i++)
      d += q[i] * b2f((unsigned short)k0[i]) + q[8 + i] * b2f((unsigned short)k1[i]);
    d += __shfl_xor(d, 1);
    d += __shfl_xor(d, 2);
    lg[s] = d;
  }
  float mx = -1e30f;
#pragma unroll
  for (int s = 0; s < 16; s++)
    if (s <= t) mx = fmaxf(mx, lg[s]);
  float den = 0.f;
#pragma unroll
  for (int s = 0; s < 16; s++) {
    float e = (s <= t) ? __expf(lg[s] - mx) : 0.f;
    lg[s] = e;
    den += e;
  }
  float inv = 1.f / den;
  float acc[16] = {};
  size_t vbase = kbase + 512;
#pragma unroll
  for (int s = 0; s < 16; s++) {
    const unsigned short* vp = qkv + vbase + (size_t)s * 1536;
    s16x8 v0 = *(const s16x8*)vp;
    s16x8 v1 = *(const s16x8*)(vp + 8);
    float a = lg[s] * inv;
#pragma unroll
    for (int i = 0; i < 8; i++) {
      acc[i] += a * b2f((unsigned short)v0[i]);
      acc[8 + i] += a * b2f((unsigned short)v1[i]);
    }
  }
  size_t orow = (size_t)(b * 16 + t) * 512 + h * 64 + p * 16;
  s16x8 r0, r1;
#pragma unroll
  for (int i = 0; i < 8; i++) {
    r0[i] = (short)f2b(acc[i]);
    r1[i] = (short)f2b(acc[8 + i]);
  }
  *(s16x8*)(o + orow) = r0;
  *(s16x8*)(o + orow + 8) = r1;
}

// ---------------- bf16 MFMA GEMM: 256x256 tile, BK=64, 8 waves ----------------
// Wave grid 2(M)x4(N); per-wave output 128x64 (8x4 fragments, 32 acc).
// LDS: A[2buf][2half][128][64] + same for B = 128 KB, global_load_lds width-16.
// Swizzle: 16B slots within a 128B row, phys = logical ^ (row&7), applied on the
// global SOURCE col at staging (LDS dest linear) and on the ds_read address.
// Pipeline: stage(t+1) issued first, counted WAITV(8) = tile t's 8 loads landed
// (never vmcnt(0) in the loop). wait -> barrier -> 64 MFMA/wave -> barrier.
enum { EPI_BF16 = 0, EPI_RESF32 = 1, EPI_RELU_BF16 = 2, EPI_YB = 3, EPI_OUTB = 4 };

template <int EPI>
__global__ __launch_bounds__(512, 2) void gemm_bt(
    const unsigned short* __restrict__ A,   // (M, K) bf16
    const unsigned short* __restrict__ Bt,  // (N, K) bf16
    int K, int N, int nT,
    const float* __restrict__ bias, const void* __restrict__ res,
    float* __restrict__ outF, unsigned short* __restrict__ outB) {
  __shared__ __align__(16) unsigned short As[2][2][128 * 64];
  __shared__ __align__(16) unsigned short Bs[2][2][128 * 64];

  int tid = threadIdx.x;
  // XCD-chunked 1D swizzle, N-fastest tile order (grids are multiples of 8)
  int lid = ((int)blockIdx.x & 7) * ((int)gridDim.x >> 3) + ((int)blockIdx.x >> 3);
  int mBase = (lid / nT) * 256;
  int nBase = (lid % nT) * 256;

  int lane = tid & 63;
  int wid = tid >> 6;     // 0..7
  int wm = wid >> 2;      // 0..1 -> A half (rows wm*128..)
  int wn = wid & 3;       // 0..3 -> B rows wn*64..
  int l15 = lane & 15;
  int s4 = lane >> 4;     // 0..3
  int lr4 = s4 * 4;

  // staging: thread covers global row srow (within 64-row chunk), 16B slot tid&7;
  // source col pre-swizzled: LDS[r][p] = global[r][p ^ (r&7)]
  int srow = tid >> 3;                        // 0..63
  int scol = ((tid & 7) ^ (srow & 7)) << 3;   // element col
  const unsigned short* pa = A + (size_t)(mBase + srow) * K + scol;
  const unsigned short* pb = Bt + (size_t)(nBase + srow) * K + scol;
  unsigned short* sbA = &As[0][0][0] + wid * 512;  // wave-uniform LDS bases
  unsigned short* sbB = &Bs[0][0][0] + wid * 512;
  size_t k64 = (size_t)64 * K;

  f32x4 acc[8][4] = {};

  auto stage = [&](int buf, int kt) {   // 8 loads/wave: chunks c -> rows c*64, lds c*4096
    unsigned short* dA = sbA + buf * 16384;
    unsigned short* dB = sbB + buf * 16384;
    gl16(pa + kt, dA);
    gl16(pa + kt + k64, dA + 4096);
    gl16(pa + kt + 2 * k64, dA + 8192);
    gl16(pa + kt + 3 * k64, dA + 12288);
    gl16(pb + kt, dB);
    gl16(pb + kt + k64, dB + 4096);
    gl16(pb + kt + 2 * k64, dB + 8192);
    gl16(pb + kt + 3 * k64, dB + 12288);
  };

  auto compute = [&](int buf) {
    const unsigned short* hA = &As[buf][wm][0];
    const unsigned short* hB = &Bs[buf][wn >> 1][0];
    int rb0 = (wn & 1) * 64;
#pragma unroll
    for (int kk = 0; kk < 2; ++kk) {
      int xs = (((kk * 4 + s4) ^ (l15 & 7)) << 3);  // swizzled 8-elem slot
      s16x8 bfr[4], afr[4];
#pragma unroll
      for (int n = 0; n < 4; ++n)
        bfr[n] = *(const s16x8*)&hB[(rb0 + n * 16 + l15) * 64 + xs];
#pragma unroll
      for (int m = 0; m < 4; ++m)
        afr[m] = *(const s16x8*)&hA[(m * 16 + l15) * 64 + xs];
#pragma unroll
      for (int m = 0; m < 4; ++m)
#pragma unroll
        for (int n = 0; n < 4; ++n)
          acc[m][n] = __builtin_amdgcn_mfma_f32_16x16x32_bf16(afr[m], bfr[n], acc[m][n], 0, 0, 0);
#pragma unroll
      for (int m = 0; m < 4; ++m)
        afr[m] = *(const s16x8*)&hA[((m + 4) * 16 + l15) * 64 + xs];
#pragma unroll
      for (int m = 0; m < 4; ++m)
#pragma unroll
        for (int n = 0; n < 4; ++n)
          acc[m + 4][n] = __builtin_amdgcn_mfma_f32_16x16x32_bf16(afr[m], bfr[n], acc[m + 4][n], 0, 0, 0);
    }
  };

  int NT = K >> 6;
  stage(0, 0);
  for (int t = 0; t < NT; ++t) {
    if (t + 1 < NT) {
      stage((t + 1) & 1, (t + 1) << 6);  // 16 in flight max
      WAITV(8);                          // tile t's 8 loads landed
    } else {
      WAITV(0);
    }
    BAR();          // all waves' loads landed -> LDS[t&1] complete
    compute(t & 1);
    BAR();          // all waves done reading before next stage overwrites
  }

#pragma unroll
  for (int n = 0; n < 4; n++) {
    int gc2 = nBase + wn * 64 + n * 16 + l15;
    float bv = (EPI == EPI_BF16) ? 0.f : bias[gc2];
#pragma unroll
    for (int m = 0; m < 8; m++) {
#pragma unroll
      for (int j = 0; j < 4; j++) {
        int gr = mBase + wm * 128 + m * 16 + lr4 + j;
        size_t off = (size_t)gr * N + gc2;
        float v = acc[m][n][j] + bv;
        if (EPI == EPI_RESF32)
          outF[off] = v + ((const float*)res)[off];
        else if (EPI == EPI_YB)
          outB[off] = f2b(v + ((const float*)res)[off]);
        else if (EPI == EPI_OUTB)
          outF[off] = v + b2f(((const unsigned short*)res)[off]);
        else if (EPI == EPI_RELU_BF16)
          outB[off] = f2b(fmaxf(v, 0.f));
        else
          outB[off] = f2b(v);
      }
    }
  }
}

// ---------------- launch ----------------
extern "C" void kernel_launch(void* const* d_in, const int* in_sizes, int n_in,
                              void* d_out, int out_size, void* d_ws, size_t ws_size,
                              hipStream_t stream) {
  const float* x      = (const float*)d_in[0];
  const float* ln1_g  = (const float*)d_in[1];
  const float* ln1_b  = (const float*)d_in[2];
  const float* wq     = (const float*)d_in[3];
  const float* wk     = (const float*)d_in[4];
  const float* wv     = (const float*)d_in[5];
  const float* w_proj = (const float*)d_in[6];
  const float* b_proj = (const float*)d_in[7];
  const float* ln2_g  = (const float*)d_in[8];
  const float* ln2_b  = (const float*)d_in[9];
  const float* w1     = (const float*)d_in[10];
  const float* b1     = (const float*)d_in[11];
  const float* w2     = (const float*)d_in[12];
  const float* b2     = (const float*)d_in[13];
  float* out = (float*)d_out;

  char* ws = (char*)d_ws;
  unsigned short* qkvT  = (unsigned short*)(ws + 0);          // 1.5 MB
  unsigned short* projT = (unsigned short*)(ws + 1572864);    // 0.5 MB
  unsigned short* w1T   = (unsigned short*)(ws + 2097152);    // 2 MB
  unsigned short* w2T   = (unsigned short*)(ws + 4194304);    // 2 MB
  unsigned short* hbuf  = (unsigned short*)(ws + 6291456);    // 67 MB (h, then h2)
  unsigned short* qkv   = (unsigned short*)(ws + 73400320);   // 201 MB; reused as ff (268 MB)
  unsigned short* obuf  = (unsigned short*)(ws + 341835776);  // 67 MB
  unsigned short* ybuf  = (unsigned short*)(ws + 408944640);  // 67 MB (bf16 y) if room
  bool yb16 = ws_size >= 476053504ull;

  pack_qkv_k<<<3072, 256, 0, stream>>>(wq, wk, wv, qkvT);
  pack_T_k<<<1024, 256, 0, stream>>>(w_proj, projT, 512, 512);
  pack_T_k<<<4096, 256, 0, stream>>>(w1, w1T, 512, 2048);
  pack_T_k<<<4096, 256, 0, stream>>>(w2, w2T, 2048, 512);

  ln_k<<<16384, 256, 0, stream>>>(x, ln1_g, ln1_b, hbuf);

  // qkv = h @ [wq|wk|wv]  (M=65536, K=512, N=1536): 256 m-tiles x 6 n-tiles
  gemm_bt<EPI_BF16><<<1536, 512, 0, stream>>>(hbuf, qkvT, 512, 1536, 6,
                                              nullptr, nullptr, nullptr, qkv);
  attn_k<<<8192, 256, 0, stream>>>(qkv, obuf);

  unsigned short* ff = qkv;  // qkv dead after attn
  if (yb16) {
    // y(bf16) = o @ w_proj + b_proj + x   (N=512: 2 n-tiles)
    gemm_bt<EPI_YB><<<512, 512, 0, stream>>>(obuf, projT, 512, 512, 2,
                                             b_proj, x, nullptr, ybuf);
    ln_b_k<<<16384, 256, 0, stream>>>(ybuf, ln2_g, ln2_b, hbuf);
    gemm_bt<EPI_RELU_BF16><<<2048, 512, 0, stream>>>(hbuf, w1T, 512, 2048, 8,
                                                     b1, nullptr, nullptr, ff);
    // out(f32) = ff @ w2 + b2 + y(bf16)   (K=2048)
    gemm_bt<EPI_OUTB><<<512, 512, 0, stream>>>(ff, w2T, 2048, 512, 2,
                                               b2, ybuf, out, nullptr);
  } else {
    gemm_bt<EPI_RESF32><<<512, 512, 0, stream>>>(obuf, projT, 512, 512, 2,
                                                 b_proj, x, out, nullptr);
    ln_k<<<16384, 256, 0, stream>>>(out, ln2_g, ln2_b, hbuf);
    gemm_bt<EPI_RELU_BF16><<<2048, 512, 0, stream>>>(hbuf, w1T, 512, 2048, 8,
                                                     b1, nullptr, nullptr, ff);
    gemm_bt<EPI_RESF32><<<512, 512, 0, stream>>>(ff, w2T, 2048, 512, 2,
                                                 b2, out, out, nullptr);
  }
}